// Round 4
// baseline (165.324 us; speedup 1.0000x reference)
//
#include <hip/hip_runtime.h>
#include <math.h>

// NetVLAD clustering layer, f32, MI355X — 3 kernels.
// x:[16,256,1500], centroids:[64,256], lin_w:[66,256], lin_b:[66]
// out: [16, 64*256] f32
//
// KA (chunk,u) 256 thr, 2 blocks/CU: stage x chunk (48 t) -> LDS; logits with
//     W read directly from global via VECTOR b128 broadcast loads (forced
//     per-lane address so the compiler cannot scalarize -> deep vmcnt
//     pipelining; no W staging, no per-fc barriers); 4-wave f-split + LDS
//     tree reduce; softmax -> Asm (LDS only); 8x8 aggregation + folded asum.
// KB (cq,u): one wave per c; 32 float4 coalesced partial loads; shuffle-only
//     norm reduction (no LDS, no barriers).
// KC: global L2 scale (float4).

#define NU 16
#define NF 256
#define NT 1500
#define NC 64
#define NCG 66          // clusters + ghosts
#define EPSN 1e-12f
#define TCH 48          // t-chunk (32 chunks cover 1536 >= 1500)
#define NCHUNK 32
#define XP 49           // LDS row stride: 49 % 32 = 17, gcd(17,32)=1 -> conflict-free

// ---------------- KA: logits + softmax + per-chunk aggregation ----------------
__global__ __launch_bounds__(256, 2) void ka_fused(
        const float* __restrict__ x, const float* __restrict__ lin_w,
        const float* __restrict__ lin_b, float* __restrict__ partial,
        float* __restrict__ asum_part) {
    __shared__ float Xsm[NF][XP];        // 50176 B
    __shared__ float Asm[NC][XP];        // 12544 B
    __shared__ float red[NCG][64];       // 16896 B
    // total 79616 B -> 2 blocks/CU, 8 waves/CU

    const int chunk = blockIdx.x, u = blockIdx.y;
    const int tid = threadIdx.x, lane = tid & 63, wave = tid >> 6;
    const int t0 = chunk * TCH;

    // ---- stage X chunk -> LDS (zero-fill past NT) ----
    {
        const int fr = tid >> 2;          // f row 0..63 (+64r)
        const int ks = (tid & 3) * 4;     // t offset 0,4,8,12
        #pragma unroll
        for (int r = 0; r < 4; ++r) {
            const int f = fr + 64 * r;
            const float* rp = x + (size_t)(u * NF + f) * NT + t0;
            #pragma unroll
            for (int q = 0; q < 3; ++q) {
                const int kk = ks + 16 * q;
                const int tg = t0 + kk;
                float4 v;
                if (tg + 3 < NT) v = *(const float4*)(rp + kk);  // 16B-aligned
                else {
                    v.x = (tg + 0 < NT) ? rp[kk + 0] : 0.0f;
                    v.y = (tg + 1 < NT) ? rp[kk + 1] : 0.0f;
                    v.z = (tg + 2 < NT) ? rp[kk + 2] : 0.0f;
                    v.w = (tg + 3 < NT) ? rp[kk + 3] : 0.0f;
                }
                Xsm[f][kk + 0] = v.x; Xsm[f][kk + 1] = v.y;
                Xsm[f][kk + 2] = v.z; Xsm[f][kk + 3] = v.w;
            }
        }
    }
    __syncthreads();

    // ---- logits: wave w accumulates f-quarter [64w, 64w+64) for 48 t's ----
    // W comes straight from global as b128 VECTOR broadcast loads. The opaque
    // per-lane zero prevents the compiler from proving wave-uniformity and
    // falling back to s_load (round-3 failure: SGPR-pressure serialization).
    float acc[NCG];
    #pragma unroll
    for (int c = 0; c < NCG; ++c) acc[c] = 0.0f;
    {
        int vzero;
        asm volatile("v_mov_b32 %0, 0" : "=v"(vzero));   // opaque 0 in a VGPR
        const int kk = (lane < TCH) ? lane : (TCH - 1);  // lanes 48-63: dup, unstored
        for (int fc = 0; fc < 4; ++fc) {
            const int fbase = wave * 64 + fc * 16;
            const float* wb = lin_w + fbase + vzero;     // per-lane (equal) address
            float xv[16];
            #pragma unroll
            for (int k = 0; k < 16; ++k) xv[k] = Xsm[fbase + k][kk];
            #pragma unroll
            for (int c = 0; c < NCG; ++c) {
                const float4* wp = (const float4*)(wb + c * NF);  // 64B-aligned
                const float4 w0 = wp[0], w1 = wp[1], w2 = wp[2], w3 = wp[3];
                acc[c] += w0.x*xv[0]  + w0.y*xv[1]  + w0.z*xv[2]  + w0.w*xv[3]
                        + w1.x*xv[4]  + w1.y*xv[5]  + w1.z*xv[6]  + w1.w*xv[7]
                        + w2.x*xv[8]  + w2.y*xv[9]  + w2.z*xv[10] + w2.w*xv[11]
                        + w3.x*xv[12] + w3.y*xv[13] + w3.z*xv[14] + w3.w*xv[15];
            }
        }
    }

    // ---- 3-round cross-wave reduce (single 66x64 buffer) ----
    {
        if (wave == 3) {
            #pragma unroll
            for (int c = 0; c < NCG; ++c) red[c][lane] = acc[c];
        }
        __syncthreads();
        if (wave == 1) {
            #pragma unroll
            for (int c = 0; c < NCG; ++c) acc[c] += red[c][lane];
        }
        __syncthreads();
        if (wave == 2) {
            #pragma unroll
            for (int c = 0; c < NCG; ++c) red[c][lane] = acc[c];
        }
        __syncthreads();
        if (wave == 0) {
            #pragma unroll
            for (int c = 0; c < NCG; ++c) acc[c] += red[c][lane];
        }
        __syncthreads();
        if (wave == 1) {
            #pragma unroll
            for (int c = 0; c < NCG; ++c) red[c][lane] = acc[c];
        }
        __syncthreads();
        if (wave == 0) {
            #pragma unroll
            for (int c = 0; c < NCG; ++c) acc[c] += red[c][lane] + lin_b[c];
            // softmax over 66, keep 64
            float m = -INFINITY;
            #pragma unroll
            for (int c = 0; c < NCG; ++c) m = fmaxf(m, acc[c]);
            float s = 0.0f;
            #pragma unroll
            for (int c = 0; c < NCG; ++c) { acc[c] = __expf(acc[c] - m); s += acc[c]; }
            const int t = t0 + lane;
            const float sc = (t < NT) ? (1.0f / s) : 0.0f;   // zero padded t's
            if (lane < TCH) {
                #pragma unroll
                for (int c = 0; c < NC; ++c) Asm[c][lane] = acc[c] * sc;
            }
        }
        __syncthreads();
    }

    // ---- 8x8 aggregation over the 48-t chunk (asum folded in) ----
    {
        float ag[8][8], as[8];
        #pragma unroll
        for (int i = 0; i < 8; ++i) {
            as[i] = 0.0f;
            #pragma unroll
            for (int j = 0; j < 8; ++j) ag[i][j] = 0.0f;
        }
        const int cb = (tid >> 5) * 8;   // 8 c's per thread-group
        const int fl = tid & 31;         // f = fl + 32j

        #pragma unroll 4
        for (int k = 0; k < TCH; ++k) {
            float av[8], xv[8];
            #pragma unroll
            for (int i = 0; i < 8; ++i) av[i] = Asm[cb + i][k];      // broadcast
            #pragma unroll
            for (int j = 0; j < 8; ++j) xv[j] = Xsm[fl + 32 * j][k]; // stride 49: conflict-free
            #pragma unroll
            for (int i = 0; i < 8; ++i) {
                as[i] += av[i];
                #pragma unroll
                for (int j = 0; j < 8; ++j) ag[i][j] += av[i] * xv[j];
            }
        }

        #pragma unroll
        for (int i = 0; i < 8; ++i) {
            float* op = partial + ((size_t)((chunk * NU + u) * NC + cb + i)) * NF;
            #pragma unroll
            for (int j = 0; j < 8; ++j) op[fl + 32 * j] = ag[i][j];
        }
        if (fl == 0) {
            #pragma unroll
            for (int i = 0; i < 8; ++i)
                asum_part[(chunk * NU + u) * NC + cb + i] = as[i];
        }
    }
}

// ---------------- KB: reduce partials + intra-normalize (wave per c) --------
__global__ __launch_bounds__(256) void kb_norm(
        const float* __restrict__ asum_part, const float* __restrict__ partial,
        const float* __restrict__ centroids, float* __restrict__ compn,
        float* __restrict__ rowsq) {
    const int u = blockIdx.y;
    const int wave = threadIdx.x >> 6, lane = threadIdx.x & 63;
    const int c = blockIdx.x * 4 + wave;         // grid.x = 16 -> c in [0,64)

    float asum = 0.0f;                           // wave-uniform -> scalar loads
    #pragma unroll
    for (int ch = 0; ch < NCHUNK; ++ch)
        asum += asum_part[(ch * NU + u) * NC + c];

    float4 val = make_float4(0.f, 0.f, 0.f, 0.f);
    #pragma unroll 8
    for (int ch = 0; ch < NCHUNK; ++ch) {
        const float4 p = *(const float4*)(
            partial + ((size_t)((ch * NU + u) * NC + c)) * NF + lane * 4);
        val.x += p.x; val.y += p.y; val.z += p.z; val.w += p.w;
    }
    const float4 ce = *(const float4*)(centroids + c * NF + lane * 4);
    val.x -= asum * ce.x; val.y -= asum * ce.y;
    val.z -= asum * ce.z; val.w -= asum * ce.w;

    float ss = val.x * val.x + val.y * val.y + val.z * val.z + val.w * val.w;
    #pragma unroll
    for (int off = 32; off > 0; off >>= 1) ss += __shfl_down(ss, off, 64);
    ss = __shfl(ss, 0, 64);                      // broadcast total

    const float d   = fmaxf(sqrtf(ss), EPSN);
    const float inv = 1.0f / d;
    float4 o;
    o.x = val.x * inv; o.y = val.y * inv; o.z = val.z * inv; o.w = val.w * inv;
    *(float4*)(compn + ((size_t)(u * NC + c)) * NF + lane * 4) = o;
    if (lane == 0) rowsq[u * NC + c] = ss / (d * d);
}

// ---------------- KC: global normalize ----------------
__global__ __launch_bounds__(256) void kc_scale(
        const float* __restrict__ compn, const float* __restrict__ rowsq,
        float* __restrict__ out) {
    const int u = blockIdx.y, sl = blockIdx.x;
    const int tid = threadIdx.x;
    float g = 0.0f;                      // uniform -> scalar loads
    #pragma unroll
    for (int c = 0; c < NC; ++c) g += rowsq[u * NC + c];
    const float inv = 1.0f / fmaxf(sqrtf(g), EPSN);
    const int base = u * (NC * NF) + sl * 1024 + tid * 4;
    float4 v = *(const float4*)(compn + base);
    v.x *= inv; v.y *= inv; v.z *= inv; v.w *= inv;
    *(float4*)(out + base) = v;
}

// ---------------- launcher ----------------
extern "C" void kernel_launch(void* const* d_in, const int* in_sizes, int n_in,
                              void* d_out, int out_size, void* d_ws, size_t ws_size,
                              hipStream_t stream) {
    (void)in_sizes; (void)n_in; (void)out_size; (void)ws_size;
    const float* x         = (const float*)d_in[0];
    const float* centroids = (const float*)d_in[1];
    const float* lin_w     = (const float*)d_in[2];
    const float* lin_b     = (const float*)d_in[3];
    float* out = (float*)d_out;

    float* ws        = (float*)d_ws;
    float* partial   = ws;                                        // 32*16*64*256 = 8,388,608 f
    float* asum_part = partial + (size_t)NCHUNK * NU * NC * NF;   // 32*16*64 = 32,768 f
    float* compn     = asum_part + NCHUNK * NU * NC;              // 262,144 f
    float* rowsq     = compn + (size_t)NU * NC * NF;              // 1,024 f (~34.7 MB)

    dim3 blk(256);
    hipLaunchKernelGGL(ka_fused, dim3(NCHUNK, NU), blk, 0, stream,
                       x, lin_w, lin_b, partial, asum_part);
    hipLaunchKernelGGL(kb_norm,  dim3(16, NU), blk, 0, stream,
                       asum_part, partial, centroids, compn, rowsq);
    hipLaunchKernelGGL(kc_scale, dim3(16, NU), blk, 0, stream,
                       compn, rowsq, out);
}